// Round 6
// baseline (861.535 us; speedup 1.0000x reference)
//
#include <hip/hip_runtime.h>
#include <hip/hip_bf16.h>
#include <math.h>

#define NROWS 16384
#define DD 4096

typedef __attribute__((ext_vector_type(8))) short short8;
typedef __attribute__((ext_vector_type(4))) float f32x4;

typedef const __attribute__((address_space(1))) void* gas_cvp;
typedef __attribute__((address_space(3))) void* las_vp;

__device__ __forceinline__ void gload_lds16(const void* g, void* l) {
  __builtin_amdgcn_global_load_lds((gas_cvp)g, (las_vp)l, 16, 0, 0);
}

// ---------------- 16-point FFT in registers (two radix-4 stages) ----------------
__device__ __forceinline__ void dft4(float ar, float ai, float br, float bi,
                                     float cr, float ci, float dr, float di,
                                     float& y0r, float& y0i, float& y1r, float& y1i,
                                     float& y2r, float& y2i, float& y3r, float& y3i) {
  float t0r = ar + cr, t0i = ai + ci;
  float t1r = ar - cr, t1i = ai - ci;
  float t2r = br + dr, t2i = bi + di;
  float t3r = br - dr, t3i = bi - di;
  y0r = t0r + t2r; y0i = t0i + t2i;
  y2r = t0r - t2r; y2i = t0i - t2i;
  y1r = t1r + t3i; y1i = t1i - t3r;
  y3r = t1r - t3i; y3i = t1i + t3r;
}

#define C16_1 0.9238795325112867f
#define S16_1 0.3826834323650898f
#define C16_2 0.7071067811865476f

__device__ __forceinline__ void fft16(float* xr, float* xi) {
  const float W16R[10] = {1.f,  C16_1,  C16_2,  S16_1, 0.f, -S16_1, -C16_2, -C16_1, -1.f, -C16_1};
  const float W16I[10] = {0.f, -S16_1, -C16_2, -C16_1, -1.f, -C16_1, -C16_2, -S16_1, 0.f,  S16_1};
  float gr[16], gi[16];
  #pragma unroll
  for (int n2 = 0; n2 < 4; ++n2) {
    dft4(xr[n2], xi[n2], xr[4 + n2], xi[4 + n2], xr[8 + n2], xi[8 + n2], xr[12 + n2], xi[12 + n2],
         gr[0 * 4 + n2], gi[0 * 4 + n2], gr[1 * 4 + n2], gi[1 * 4 + n2],
         gr[2 * 4 + n2], gi[2 * 4 + n2], gr[3 * 4 + n2], gi[3 * 4 + n2]);
  }
  #pragma unroll
  for (int k1 = 1; k1 < 4; ++k1) {
    #pragma unroll
    for (int n2 = 1; n2 < 4; ++n2) {
      const float wr = W16R[k1 * n2], wi = W16I[k1 * n2];
      float a = gr[k1 * 4 + n2], b = gi[k1 * 4 + n2];
      gr[k1 * 4 + n2] = a * wr - b * wi;
      gi[k1 * 4 + n2] = a * wi + b * wr;
    }
  }
  #pragma unroll
  for (int k1 = 0; k1 < 4; ++k1) {
    dft4(gr[k1 * 4 + 0], gi[k1 * 4 + 0], gr[k1 * 4 + 1], gi[k1 * 4 + 1],
         gr[k1 * 4 + 2], gi[k1 * 4 + 2], gr[k1 * 4 + 3], gi[k1 * 4 + 3],
         xr[k1 + 0], xi[k1 + 0], xr[k1 + 4], xi[k1 + 4],
         xr[k1 + 8], xi[k1 + 8], xr[k1 + 12], xi[k1 + 12]);
  }
}

// twiddle apply x[k] *= w1^k via power-doubling (dep depth 4, not 15)
#define TWIDDLE16(xr, xi, w1r, w1i)                                               \
  {                                                                               \
    float pr[16], pi[16];                                                         \
    pr[1] = (w1r); pi[1] = (w1i);                                                 \
    _Pragma("unroll") for (int _z = 0; _z < 1; ++_z) {                            \
      pr[2] = pr[1]*pr[1] - pi[1]*pi[1];  pi[2] = 2.f*pr[1]*pi[1];                \
      pr[4] = pr[2]*pr[2] - pi[2]*pi[2];  pi[4] = 2.f*pr[2]*pi[2];                \
      pr[8] = pr[4]*pr[4] - pi[4]*pi[4];  pi[8] = 2.f*pr[4]*pi[4];                \
      pr[3] = pr[1]*pr[2] - pi[1]*pi[2];  pi[3] = pr[1]*pi[2] + pi[1]*pr[2];      \
      pr[5] = pr[1]*pr[4] - pi[1]*pi[4];  pi[5] = pr[1]*pi[4] + pi[1]*pr[4];      \
      pr[6] = pr[2]*pr[4] - pi[2]*pi[4];  pi[6] = pr[2]*pi[4] + pi[2]*pr[4];      \
      pr[7] = pr[3]*pr[4] - pi[3]*pi[4];  pi[7] = pr[3]*pi[4] + pi[3]*pr[4];      \
      pr[9] = pr[1]*pr[8] - pi[1]*pi[8];  pi[9] = pr[1]*pi[8] + pi[1]*pr[8];      \
      pr[10] = pr[2]*pr[8] - pi[2]*pi[8]; pi[10] = pr[2]*pi[8] + pi[2]*pr[8];     \
      pr[11] = pr[3]*pr[8] - pi[3]*pi[8]; pi[11] = pr[3]*pi[8] + pi[3]*pr[8];     \
      pr[12] = pr[4]*pr[8] - pi[4]*pi[8]; pi[12] = pr[4]*pi[8] + pi[4]*pr[8];     \
      pr[13] = pr[5]*pr[8] - pi[5]*pi[8]; pi[13] = pr[5]*pi[8] + pi[5]*pr[8];     \
      pr[14] = pr[6]*pr[8] - pi[6]*pi[8]; pi[14] = pr[6]*pi[8] + pi[6]*pr[8];     \
      pr[15] = pr[7]*pr[8] - pi[7]*pi[8]; pi[15] = pr[7]*pi[8] + pi[7]*pr[8];     \
    }                                                                             \
    _Pragma("unroll") for (int k = 1; k < 16; ++k) {                              \
      float aa = (xr)[k], bb = (xi)[k];                                           \
      (xr)[k] = aa * pr[k] - bb * pi[k];                                          \
      (xi)[k] = aa * pi[k] + bb * pr[k];                                          \
    }                                                                             \
  }

// ---------------- FFT magnitude + row-max normalize -> bf16 A ----------------
__global__ __launch_bounds__(256) void k_fftmag(const float* __restrict__ x,
                                                __hip_bfloat16* __restrict__ A) {
  __shared__ float lre[16 * 272];
  __shared__ float lim[16 * 272];
  const int t = threadIdx.x;
  const size_t row = blockIdx.x;
  const float* __restrict__ xg = x + row * DD;

  float xr[16], xi[16];

  #pragma unroll
  for (int n1 = 0; n1 < 16; ++n1) {
    xr[n1] = xg[n1 * 256 + t];
    xi[n1] = 0.0f;
  }
  fft16(xr, xi);
  {
    float w1r, w1i;
    __sincosf(-6.283185307179586f * (float)t / 4096.0f, &w1i, &w1r);
    TWIDDLE16(xr, xi, w1r, w1i);
  }
  #pragma unroll
  for (int k1 = 0; k1 < 16; ++k1) {
    lre[k1 * 272 + t] = xr[k1];
    lim[k1 * 272 + t] = xi[k1];
  }
  __syncthreads();

  const int k1 = t >> 4;
  const int m2 = t & 15;
  #pragma unroll
  for (int m1 = 0; m1 < 16; ++m1) {
    xr[m1] = lre[k1 * 272 + m1 * 16 + m2];
    xi[m1] = lim[k1 * 272 + m1 * 16 + m2];
  }
  fft16(xr, xi);
  {
    float w1r, w1i;
    __sincosf(-6.283185307179586f * (float)m2 / 256.0f, &w1i, &w1r);
    TWIDDLE16(xr, xi, w1r, w1i);
  }
  __syncthreads();
  #pragma unroll
  for (int j1 = 0; j1 < 16; ++j1) {
    lre[j1 * 256 + k1 * 16 + (m2 ^ j1)] = xr[j1];
    lim[j1 * 256 + k1 * 16 + (m2 ^ j1)] = xi[j1];
  }
  __syncthreads();

  const int j1 = t & 15;
  #pragma unroll
  for (int mm = 0; mm < 16; ++mm) {
    xr[mm] = lre[j1 * 256 + k1 * 16 + (mm ^ j1)];
    xi[mm] = lim[j1 * 256 + k1 * 16 + (mm ^ j1)];
  }
  fft16(xr, xi);

  float mag[16];
  float mx = 0.0f;
  #pragma unroll
  for (int j2 = 0; j2 < 16; ++j2) {
    float m = sqrtf(xr[j2] * xr[j2] + xi[j2] * xi[j2]);
    mag[j2] = m;
    mx = fmaxf(mx, m);
  }
  #pragma unroll
  for (int off = 32; off > 0; off >>= 1) mx = fmaxf(mx, __shfl_xor(mx, off));
  __shared__ float wmax[4];
  if ((t & 63) == 0) wmax[t >> 6] = mx;
  __syncthreads();
  mx = fmaxf(fmaxf(wmax[0], wmax[1]), fmaxf(wmax[2], wmax[3]));
  const float inv = 1.0f / (mx + 1e-6f);
  #pragma unroll
  for (int j2 = 0; j2 < 16; ++j2) {
    A[row * DD + (size_t)(k1 + 16 * j1 + 256 * j2)] = __float2bfloat16(mag[j2] * inv);
  }
}

// ---------------- Sinkhorn: log_P = w - r_i - c_j (outer form) ----------------
__device__ __forceinline__ void lse_acc(float& m, float& s, float v) {
  float nm = fmaxf(m, v);
  s = s * __expf(m - nm) + __expf(v - nm);
  m = nm;
}
__device__ __forceinline__ void lse_merge(float& m, float& s, float m2, float s2) {
  float nm = fmaxf(m, m2);
  s = s * __expf(m - nm) + s2 * __expf(m2 - nm);
  m = nm;
}

// r_i = lse_j(w_ij - c_j); one block per row, float4 loads; c may be null (== 0)
__global__ __launch_bounds__(256) void k_row_lse(const float* __restrict__ w,
                                                 const float* __restrict__ c,
                                                 float* __restrict__ r) {
  const int i = blockIdx.x;
  const int t = threadIdx.x;
  const f32x4* __restrict__ wr4 = (const f32x4*)(w + (size_t)i * DD);
  const f32x4* __restrict__ c4 = (const f32x4*)c;
  float m = -INFINITY, s = 0.0f;
  #pragma unroll
  for (int u = 0; u < 4; ++u) {
    int j4 = t + u * 256;
    f32x4 wv = wr4[j4];
    f32x4 cv;
    if (c4) cv = c4[j4];
    else { cv[0] = 0.f; cv[1] = 0.f; cv[2] = 0.f; cv[3] = 0.f; }
    #pragma unroll
    for (int q = 0; q < 4; ++q) lse_acc(m, s, wv[q] - cv[q]);
  }
  #pragma unroll
  for (int off = 32; off > 0; off >>= 1) {
    float m2 = __shfl_xor(m, off);
    float s2 = __shfl_xor(s, off);
    lse_merge(m, s, m2, s2);
  }
  __shared__ float sm[4], ss[4];
  if ((t & 63) == 0) { sm[t >> 6] = m; ss[t >> 6] = s; }
  __syncthreads();
  if (t == 0) {
    float M = sm[0], S = ss[0];
    lse_merge(M, S, sm[1], ss[1]);
    lse_merge(M, S, sm[2], ss[2]);
    lse_merge(M, S, sm[3], ss[3]);
    r[i] = M + __logf(S);
  }
}

// partial col lse over 64-row chunks (256 blocks -> 1/CU); thread = 4 cols
__global__ __launch_bounds__(256) void k_col_partial(const float* __restrict__ w,
                                                     const float* __restrict__ r,
                                                     float* __restrict__ pm,
                                                     float* __restrict__ ps) {
  const int j4 = blockIdx.x * 256 + threadIdx.x;   // 0..1023
  const int i0 = blockIdx.y * 64;
  float m0 = -INFINITY, m1 = -INFINITY, m2 = -INFINITY, m3 = -INFINITY;
  float s0 = 0.f, s1 = 0.f, s2 = 0.f, s3 = 0.f;
  const f32x4* __restrict__ w4 = (const f32x4*)w;
  #pragma unroll 4
  for (int ii = 0; ii < 64; ++ii) {
    const int i = i0 + ii;
    const float rr = r[i];
    f32x4 v = w4[(size_t)i * (DD / 4) + j4];
    lse_acc(m0, s0, v[0] - rr);
    lse_acc(m1, s1, v[1] - rr);
    lse_acc(m2, s2, v[2] - rr);
    lse_acc(m3, s3, v[3] - rr);
  }
  f32x4 mv; mv[0] = m0; mv[1] = m1; mv[2] = m2; mv[3] = m3;
  f32x4 sv; sv[0] = s0; sv[1] = s1; sv[2] = s2; sv[3] = s3;
  ((f32x4*)pm)[(size_t)blockIdx.y * (DD / 4) + j4] = mv;
  ((f32x4*)ps)[(size_t)blockIdx.y * (DD / 4) + j4] = sv;
}

__global__ __launch_bounds__(256) void k_col_final(const float* __restrict__ pm,
                                                   const float* __restrict__ ps,
                                                   float* __restrict__ c) {
  const int j4 = blockIdx.x * 256 + threadIdx.x;  // 0..1023
  const f32x4* __restrict__ pm4 = (const f32x4*)pm;
  const f32x4* __restrict__ ps4 = (const f32x4*)ps;
  float m0 = -INFINITY, m1 = -INFINITY, m2 = -INFINITY, m3 = -INFINITY;
  float s0 = 0.f, s1 = 0.f, s2 = 0.f, s3 = 0.f;
  #pragma unroll 4
  for (int k = 0; k < 64; ++k) {
    f32x4 mv = pm4[(size_t)k * (DD / 4) + j4];
    f32x4 sv = ps4[(size_t)k * (DD / 4) + j4];
    lse_merge(m0, s0, mv[0], sv[0]);
    lse_merge(m1, s1, mv[1], sv[1]);
    lse_merge(m2, s2, mv[2], sv[2]);
    lse_merge(m3, s3, mv[3], sv[3]);
  }
  f32x4 cv;
  cv[0] = m0 + __logf(s0);
  cv[1] = m1 + __logf(s1);
  cv[2] = m2 + __logf(s2);
  cv[3] = m3 + __logf(s3);
  ((f32x4*)c)[j4] = cv;
}

// P = exp(w - r - c) -> f32 out; also bf16 P^T into ws (LDS tiled transpose)
__global__ __launch_bounds__(256) void k_pfinal(const float* __restrict__ w,
                                                const float* __restrict__ r,
                                                const float* __restrict__ c,
                                                float* __restrict__ P,
                                                __hip_bfloat16* __restrict__ Bt) {
  __shared__ __hip_bfloat16 tile[64][68];
  const int t = threadIdx.x;
  const int txg = t & 15;   // col group of 4
  const int ty = t >> 4;    // 0..15
  const int bi = blockIdx.y * 64;
  const int bj = blockIdx.x * 64;
  const f32x4* __restrict__ w4 = (const f32x4*)w;
  const f32x4* __restrict__ c4 = (const f32x4*)c;
  f32x4* __restrict__ P4 = (f32x4*)P;
  #pragma unroll
  for (int p = 0; p < 4; ++p) {
    int rr = p * 16 + ty;
    int gi = bi + rr;
    int gj4 = (bj >> 2) + txg;
    f32x4 wv = w4[(size_t)gi * (DD / 4) + gj4];
    f32x4 cv = c4[gj4];
    const float ri = r[gi];
    f32x4 pv;
    #pragma unroll
    for (int q = 0; q < 4; ++q) {
      pv[q] = __expf(wv[q] - ri - cv[q]);
      tile[rr][txg * 4 + q] = __float2bfloat16(pv[q]);
    }
    P4[(size_t)gi * (DD / 4) + gj4] = pv;
  }
  __syncthreads();
  typedef __attribute__((ext_vector_type(4))) short short4v;
  #pragma unroll
  for (int p = 0; p < 4; ++p) {
    int rr = p * 16 + ty;       // row of Bt-tile = col of P-tile
    int gj = bj + rr;
    short4v o;
    #pragma unroll
    for (int q = 0; q < 4; ++q)
      o[q] = *(const short*)&tile[txg * 4 + q][rr];
    *(short4v*)&Bt[(size_t)gj * DD + bi + txg * 4] = o;
  }
}

// ---------------- GEMM: 256x256 tile, BK=64, 8-phase, persistent 4 M-subtiles --
// Grid 256 = 1 block/CU. Each block: fixed N-tile, 4 consecutive M-tiles.
// Sub-tile boundary: issue next prologue stages BEFORE epilogue stores so the
// HBM fill hides under the C-writes; final K-iteration uses no-stage variants
// + vmcnt(0) so no stale in-flight gload_lds races the boundary stages.
__global__ __launch_bounds__(512, 2) void k_gemm256(const __hip_bfloat16* __restrict__ A,
                                                    const __hip_bfloat16* __restrict__ Bt,
                                                    float* __restrict__ C) {
  __shared__ alignas(16) char lds[131072];
  const int tid = threadIdx.x;
  const int lane = tid & 63;
  const int wid = tid >> 6;
  const int wm = wid >> 2;   // 0..1
  const int wn = wid & 3;    // 0..3

  // XCD-aware swizzle: 256 wgs = 8 XCDs x 32 (bijective)
  const int bid = blockIdx.x;
  const int swz = (bid & 7) * 32 + (bid >> 3);
  const int ntile = swz & 15;   // 0..15
  const int mgroup = swz >> 4;  // 0..15
  const size_t brow = (size_t)ntile * 256;

  const int srow = tid >> 2;
  const int scolb = ((tid & 3) << 4) ^ (((tid >> 5) & 1) << 5);
  const __hip_bfloat16* gB = Bt + (brow + srow) * (size_t)DD + (scolb >> 1);
  const __hip_bfloat16* gAcur =
      A + ((size_t)mgroup * 4 * 256 + srow) * (size_t)DD + (scolb >> 1);

#define STG(gbase, regionoff, kt, ks) do {                                        \
    const __hip_bfloat16* _g = (gbase) + (kt) * 64 + (ks) * 32;                   \
    char* _l = lds + (regionoff) + (((kt) & 1) * 32768) + (ks) * 16384 + tid * 16;\
    gload_lds16(_g, _l);                                                          \
    gload_lds16(_g + (size_t)128 * DD, _l + 8192);                                \
  } while (0)
#define STG_A(kt, ks) STG(gAcur, 0, kt, ks)
#define STG_B(kt, ks) STG(gB, 65536, kt, ks)

  // read addressing: lane reads row = base + (lane&15), 16B at swizzled col
  const int lr = lane & 15;
  const int rcol = ((lane >> 4) << 4) ^ (((lr >> 3) & 1) << 5);
  const int rbA = (wm * 128 + lr) * 64 + rcol;
  const int rbB = (wn * 64 + lr) * 64 + rcol;

#define LD8(off) (*reinterpret_cast<const short8*>(lds + (off)))
#define RD_B(BUF, KS)                                                   \
  { b[0] = LD8(65536 + (BUF) * 32768 + (KS) * 16384 + rbB + 0);         \
    b[1] = LD8(65536 + (BUF) * 32768 + (KS) * 16384 + rbB + 1024);      \
    b[2] = LD8(65536 + (BUF) * 32768 + (KS) * 16384 + rbB + 2048);      \
    b[3] = LD8(65536 + (BUF) * 32768 + (KS) * 16384 + rbB + 3072); }
#define RD_A4(BUF, KS, MH, DST)                                                   \
  { a[(DST) + 0] = LD8((BUF) * 32768 + (KS) * 16384 + rbA + (MH) * 4096 + 0);     \
    a[(DST) + 1] = LD8((BUF) * 32768 + (KS) * 16384 + rbA + (MH) * 4096 + 1024);  \
    a[(DST) + 2] = LD8((BUF) * 32768 + (KS) * 16384 + rbA + (MH) * 4096 + 2048);  \
    a[(DST) + 3] = LD8((BUF) * 32768 + (KS) * 16384 + rbA + (MH) * 4096 + 3072); }

#define BAR __builtin_amdgcn_s_barrier()
#define LGKM0 asm volatile("s_waitcnt lgkmcnt(0)" ::: "memory")
#define VM6 asm volatile("s_waitcnt vmcnt(6)" ::: "memory")
#define VM0 asm volatile("s_waitcnt vmcnt(0)" ::: "memory")

#define MFMA16(MH)                                                                \
  __builtin_amdgcn_s_setprio(1);                                                  \
  { _Pragma("unroll") for (int i = 0; i < 4; ++i) {                               \
      _Pragma("unroll") for (int n = 0; n < 4; ++n) {                             \
        acc[(MH) * 4 + i][n] = __builtin_amdgcn_mfma_f32_16x16x32_bf16(           \
            a[(MH) * 4 + i], b[n], acc[(MH) * 4 + i][n], 0, 0, 0); } } }          \
  __builtin_amdgcn_s_setprio(0);

#define KTILE(BUF, TN1, TN2)            \
  RD_B(BUF, 0); RD_A4(BUF, 0, 0, 0);    \
  STG_B(TN1, 1);                        \
  BAR; LGKM0; MFMA16(0); BAR;           \
  RD_A4(BUF, 0, 1, 4);                  \
  STG_B(TN2, 0);                        \
  BAR; LGKM0; MFMA16(1); BAR;           \
  RD_B(BUF, 1); RD_A4(BUF, 1, 0, 0); RD_A4(BUF, 1, 1, 4); \
  STG_A(TN2, 0);                        \
  BAR; LGKM0; MFMA16(0); BAR;           \
  STG_A(TN2, 1); VM6;                   \
  BAR; LGKM0; MFMA16(1); BAR;

  // final K-tile pair (kt=62,63): only B(63,ks1) still needs staging; no other
  // stages, and a vmcnt(0) so nothing is in flight at the sub-tile boundary.
#define KTILE_F0                        \
  RD_B(0, 0); RD_A4(0, 0, 0, 0);        \
  STG_B(63, 1);                         \
  BAR; LGKM0; MFMA16(0); BAR;           \
  RD_A4(0, 0, 1, 4);                    \
  BAR; LGKM0; MFMA16(1); BAR;           \
  RD_B(0, 1); RD_A4(0, 1, 0, 0); RD_A4(0, 1, 1, 4); \
  BAR; LGKM0; MFMA16(0); BAR;           \
  VM0;                                  \
  BAR; LGKM0; MFMA16(1); BAR;

#define KTILE_F1                        \
  RD_B(1, 0); RD_A4(1, 0, 0, 0);        \
  BAR; LGKM0; MFMA16(0); BAR;           \
  RD_A4(1, 0, 1, 4);                    \
  BAR; LGKM0; MFMA16(1); BAR;           \
  RD_B(1, 1); RD_A4(1, 1, 0, 0); RD_A4(1, 1, 1, 4); \
  BAR; LGKM0; MFMA16(0); BAR;           \
  BAR; LGKM0; MFMA16(1); BAR;

  f32x4 acc[8][4];
  short8 a[8], b[4];

  // cold prologue: tile 0 (all 4 halves) + tile 1 {B0,A0,A1}
  STG_B(0, 0); STG_A(0, 0); STG_A(0, 1); STG_B(0, 1);
  STG_B(1, 0); STG_A(1, 0); STG_A(1, 1);
  VM6;
  BAR;

  for (int st = 0; st < 4; ++st) {
    #pragma unroll
    for (int i = 0; i < 8; ++i)
      #pragma unroll
      for (int n = 0; n < 4; ++n) {
        acc[i][n][0] = 0.f; acc[i][n][1] = 0.f; acc[i][n][2] = 0.f; acc[i][n][3] = 0.f;
      }

    for (int kt = 0; kt < 62; kt += 2) {
      KTILE(0, kt + 1, kt + 2);
      KTILE(1, kt + 2, kt + 3);
    }
    KTILE_F0;
    KTILE_F1;

    const size_t arow = (size_t)(mgroup * 4 + st) * 256;

    if (st < 3) {
      // boundary prologue for next sub-tile (before stores -> fill hides)
      const __hip_bfloat16* gAn = gAcur + (size_t)256 * DD;
      STG(gB, 65536, 0, 0); STG(gAn, 0, 0, 0); STG(gAn, 0, 0, 1); STG(gB, 65536, 0, 1);
      STG(gB, 65536, 1, 0); STG(gAn, 0, 1, 0); STG(gAn, 0, 1, 1);
      gAcur = gAn;
    }

    // epilogue: C/D layout col = lane&15, row = (lane>>4)*4 + reg
    const int orow = (lane >> 4) * 4;
    const int ocol = lane & 15;
    #pragma unroll
    for (int mh = 0; mh < 2; ++mh) {
      #pragma unroll
      for (int i = 0; i < 4; ++i) {
        #pragma unroll
        for (int n = 0; n < 4; ++n) {
          #pragma unroll
          for (int jj = 0; jj < 4; ++jj) {
            size_t rrow = arow + (size_t)wm * 128 + mh * 64 + i * 16 + orow + jj;
            size_t ccol = brow + (size_t)wn * 64 + n * 16 + ocol;
            C[rrow * DD + ccol] = acc[mh * 4 + i][n][jj];
          }
        }
      }
    }

    if (st < 3) { VM6; BAR; }
  }
#undef STG
#undef STG_A
#undef STG_B
#undef LD8
#undef RD_B
#undef RD_A4
#undef BAR
#undef LGKM0
#undef VM6
#undef VM0
#undef MFMA16
#undef KTILE
#undef KTILE_F0
#undef KTILE_F1
}

extern "C" void kernel_launch(void* const* d_in, const int* in_sizes, int n_in,
                              void* d_out, int out_size, void* d_ws, size_t ws_size,
                              hipStream_t stream) {
  const float* x = (const float*)d_in[0];
  const float* w = (const float*)d_in[1];
  float* outMM = (float*)d_out;                        // [16384][4096]
  float* outP = (float*)d_out + (size_t)NROWS * DD;    // [4096][4096]

  char* ws = (char*)d_ws;
  __hip_bfloat16* A = (__hip_bfloat16*)ws;                                   // 128MB
  __hip_bfloat16* Bt = (__hip_bfloat16*)(ws + (size_t)NROWS * DD * 2);       // 32MB
  float* r = (float*)(ws + (size_t)NROWS * DD * 2 + (size_t)DD * DD * 2);
  float* c = r + DD;
  float* pm = c + DD;
  float* ps = pm + 64 * DD;

  k_fftmag<<<NROWS, 256, 0, stream>>>(x, A);
  for (int it = 0; it < 5; ++it) {
    k_row_lse<<<DD, 256, 0, stream>>>(w, it == 0 ? (const float*)nullptr : c, r);
    k_col_partial<<<dim3(4, 64), 256, 0, stream>>>(w, r, pm, ps);
    k_col_final<<<4, 256, 0, stream>>>(pm, ps, c);
  }
  k_pfinal<<<dim3(64, 64), 256, 0, stream>>>(w, r, c, outP, Bt);
  k_gemm256<<<256, 512, 0, stream>>>(A, Bt, outMM);
}

// Round 7
// 859.832 us; speedup vs baseline: 1.0020x; 1.0020x over previous
//
#include <hip/hip_runtime.h>
#include <hip/hip_bf16.h>
#include <math.h>

#define NROWS 16384
#define DD 4096

typedef __attribute__((ext_vector_type(8))) short short8;
typedef __attribute__((ext_vector_type(4))) float f32x4;

typedef const __attribute__((address_space(1))) void* gas_cvp;
typedef __attribute__((address_space(3))) void* las_vp;

__device__ __forceinline__ void gload_lds16(const void* g, void* l) {
  __builtin_amdgcn_global_load_lds((gas_cvp)g, (las_vp)l, 16, 0, 0);
}

// ---------------- 16-point FFT in registers (two radix-4 stages) ----------------
__device__ __forceinline__ void dft4(float ar, float ai, float br, float bi,
                                     float cr, float ci, float dr, float di,
                                     float& y0r, float& y0i, float& y1r, float& y1i,
                                     float& y2r, float& y2i, float& y3r, float& y3i) {
  float t0r = ar + cr, t0i = ai + ci;
  float t1r = ar - cr, t1i = ai - ci;
  float t2r = br + dr, t2i = bi + di;
  float t3r = br - dr, t3i = bi - di;
  y0r = t0r + t2r; y0i = t0i + t2i;
  y2r = t0r - t2r; y2i = t0i - t2i;
  y1r = t1r + t3i; y1i = t1i - t3r;
  y3r = t1r - t3i; y3i = t1i + t3r;
}

#define C16_1 0.9238795325112867f
#define S16_1 0.3826834323650898f
#define C16_2 0.7071067811865476f

__device__ __forceinline__ void fft16(float* xr, float* xi) {
  const float W16R[10] = {1.f,  C16_1,  C16_2,  S16_1, 0.f, -S16_1, -C16_2, -C16_1, -1.f, -C16_1};
  const float W16I[10] = {0.f, -S16_1, -C16_2, -C16_1, -1.f, -C16_1, -C16_2, -S16_1, 0.f,  S16_1};
  float gr[16], gi[16];
  #pragma unroll
  for (int n2 = 0; n2 < 4; ++n2) {
    dft4(xr[n2], xi[n2], xr[4 + n2], xi[4 + n2], xr[8 + n2], xi[8 + n2], xr[12 + n2], xi[12 + n2],
         gr[0 * 4 + n2], gi[0 * 4 + n2], gr[1 * 4 + n2], gi[1 * 4 + n2],
         gr[2 * 4 + n2], gi[2 * 4 + n2], gr[3 * 4 + n2], gi[3 * 4 + n2]);
  }
  #pragma unroll
  for (int k1 = 1; k1 < 4; ++k1) {
    #pragma unroll
    for (int n2 = 1; n2 < 4; ++n2) {
      const float wr = W16R[k1 * n2], wi = W16I[k1 * n2];
      float a = gr[k1 * 4 + n2], b = gi[k1 * 4 + n2];
      gr[k1 * 4 + n2] = a * wr - b * wi;
      gi[k1 * 4 + n2] = a * wi + b * wr;
    }
  }
  #pragma unroll
  for (int k1 = 0; k1 < 4; ++k1) {
    dft4(gr[k1 * 4 + 0], gi[k1 * 4 + 0], gr[k1 * 4 + 1], gi[k1 * 4 + 1],
         gr[k1 * 4 + 2], gi[k1 * 4 + 2], gr[k1 * 4 + 3], gi[k1 * 4 + 3],
         xr[k1 + 0], xi[k1 + 0], xr[k1 + 4], xi[k1 + 4],
         xr[k1 + 8], xi[k1 + 8], xr[k1 + 12], xi[k1 + 12]);
  }
}

// twiddle apply x[k] *= w1^k via power-doubling (dep depth 4, not 15)
#define TWIDDLE16(xr, xi, w1r, w1i)                                               \
  {                                                                               \
    float pr[16], pi[16];                                                         \
    pr[1] = (w1r); pi[1] = (w1i);                                                 \
    _Pragma("unroll") for (int _z = 0; _z < 1; ++_z) {                            \
      pr[2] = pr[1]*pr[1] - pi[1]*pi[1];  pi[2] = 2.f*pr[1]*pi[1];                \
      pr[4] = pr[2]*pr[2] - pi[2]*pi[2];  pi[4] = 2.f*pr[2]*pi[2];                \
      pr[8] = pr[4]*pr[4] - pi[4]*pi[4];  pi[8] = 2.f*pr[4]*pi[4];                \
      pr[3] = pr[1]*pr[2] - pi[1]*pi[2];  pi[3] = pr[1]*pi[2] + pi[1]*pr[2];      \
      pr[5] = pr[1]*pr[4] - pi[1]*pi[4];  pi[5] = pr[1]*pi[4] + pi[1]*pr[4];      \
      pr[6] = pr[2]*pr[4] - pi[2]*pi[4];  pi[6] = pr[2]*pi[4] + pi[2]*pr[4];      \
      pr[7] = pr[3]*pr[4] - pi[3]*pi[4];  pi[7] = pr[3]*pi[4] + pi[3]*pr[4];      \
      pr[9] = pr[1]*pr[8] - pi[1]*pi[8];  pi[9] = pr[1]*pi[8] + pi[1]*pr[8];      \
      pr[10] = pr[2]*pr[8] - pi[2]*pi[8]; pi[10] = pr[2]*pi[8] + pi[2]*pr[8];     \
      pr[11] = pr[3]*pr[8] - pi[3]*pi[8]; pi[11] = pr[3]*pi[8] + pi[3]*pr[8];     \
      pr[12] = pr[4]*pr[8] - pi[4]*pi[8]; pi[12] = pr[4]*pi[8] + pi[4]*pr[8];     \
      pr[13] = pr[5]*pr[8] - pi[5]*pi[8]; pi[13] = pr[5]*pi[8] + pi[5]*pr[8];     \
      pr[14] = pr[6]*pr[8] - pi[6]*pi[8]; pi[14] = pr[6]*pi[8] + pi[6]*pr[8];     \
      pr[15] = pr[7]*pr[8] - pi[7]*pi[8]; pi[15] = pr[7]*pi[8] + pi[7]*pr[8];     \
    }                                                                             \
    _Pragma("unroll") for (int k = 1; k < 16; ++k) {                              \
      float aa = (xr)[k], bb = (xi)[k];                                           \
      (xr)[k] = aa * pr[k] - bb * pi[k];                                          \
      (xi)[k] = aa * pi[k] + bb * pr[k];                                          \
    }                                                                             \
  }

// ---------------- FFT magnitude + row-max normalize -> bf16 A ----------------
__global__ __launch_bounds__(256) void k_fftmag(const float* __restrict__ x,
                                                __hip_bfloat16* __restrict__ A) {
  __shared__ float lre[16 * 272];
  __shared__ float lim[16 * 272];
  const int t = threadIdx.x;
  const size_t row = blockIdx.x;
  const float* __restrict__ xg = x + row * DD;

  float xr[16], xi[16];

  #pragma unroll
  for (int n1 = 0; n1 < 16; ++n1) {
    xr[n1] = xg[n1 * 256 + t];
    xi[n1] = 0.0f;
  }
  fft16(xr, xi);
  {
    float w1r, w1i;
    __sincosf(-6.283185307179586f * (float)t / 4096.0f, &w1i, &w1r);
    TWIDDLE16(xr, xi, w1r, w1i);
  }
  #pragma unroll
  for (int k1 = 0; k1 < 16; ++k1) {
    lre[k1 * 272 + t] = xr[k1];
    lim[k1 * 272 + t] = xi[k1];
  }
  __syncthreads();

  const int k1 = t >> 4;
  const int m2 = t & 15;
  #pragma unroll
  for (int m1 = 0; m1 < 16; ++m1) {
    xr[m1] = lre[k1 * 272 + m1 * 16 + m2];
    xi[m1] = lim[k1 * 272 + m1 * 16 + m2];
  }
  fft16(xr, xi);
  {
    float w1r, w1i;
    __sincosf(-6.283185307179586f * (float)m2 / 256.0f, &w1i, &w1r);
    TWIDDLE16(xr, xi, w1r, w1i);
  }
  __syncthreads();
  #pragma unroll
  for (int j1 = 0; j1 < 16; ++j1) {
    lre[j1 * 256 + k1 * 16 + (m2 ^ j1)] = xr[j1];
    lim[j1 * 256 + k1 * 16 + (m2 ^ j1)] = xi[j1];
  }
  __syncthreads();

  const int j1 = t & 15;
  #pragma unroll
  for (int mm = 0; mm < 16; ++mm) {
    xr[mm] = lre[j1 * 256 + k1 * 16 + (mm ^ j1)];
    xi[mm] = lim[j1 * 256 + k1 * 16 + (mm ^ j1)];
  }
  fft16(xr, xi);

  float mag[16];
  float mx = 0.0f;
  #pragma unroll
  for (int j2 = 0; j2 < 16; ++j2) {
    float m = sqrtf(xr[j2] * xr[j2] + xi[j2] * xi[j2]);
    mag[j2] = m;
    mx = fmaxf(mx, m);
  }
  #pragma unroll
  for (int off = 32; off > 0; off >>= 1) mx = fmaxf(mx, __shfl_xor(mx, off));
  __shared__ float wmax[4];
  if ((t & 63) == 0) wmax[t >> 6] = mx;
  __syncthreads();
  mx = fmaxf(fmaxf(wmax[0], wmax[1]), fmaxf(wmax[2], wmax[3]));
  const float inv = 1.0f / (mx + 1e-6f);
  #pragma unroll
  for (int j2 = 0; j2 < 16; ++j2) {
    A[row * DD + (size_t)(k1 + 16 * j1 + 256 * j2)] = __float2bfloat16(mag[j2] * inv);
  }
}

// ---------------- Sinkhorn: log_P = w - r_i - c_j (outer form) ----------------
__device__ __forceinline__ void lse_acc(float& m, float& s, float v) {
  float nm = fmaxf(m, v);
  s = s * __expf(m - nm) + __expf(v - nm);
  m = nm;
}
__device__ __forceinline__ void lse_merge(float& m, float& s, float m2, float s2) {
  float nm = fmaxf(m, m2);
  s = s * __expf(m - nm) + s2 * __expf(m2 - nm);
  m = nm;
}

// r_i = lse_j(w_ij - c_j); one block per row, float4 loads; c may be null (== 0)
__global__ __launch_bounds__(256) void k_row_lse(const float* __restrict__ w,
                                                 const float* __restrict__ c,
                                                 float* __restrict__ r) {
  const int i = blockIdx.x;
  const int t = threadIdx.x;
  const f32x4* __restrict__ wr4 = (const f32x4*)(w + (size_t)i * DD);
  const f32x4* __restrict__ c4 = (const f32x4*)c;
  float m = -INFINITY, s = 0.0f;
  #pragma unroll
  for (int u = 0; u < 4; ++u) {
    int j4 = t + u * 256;
    f32x4 wv = wr4[j4];
    f32x4 cv;
    if (c4) cv = c4[j4];
    else { cv[0] = 0.f; cv[1] = 0.f; cv[2] = 0.f; cv[3] = 0.f; }
    #pragma unroll
    for (int q = 0; q < 4; ++q) lse_acc(m, s, wv[q] - cv[q]);
  }
  #pragma unroll
  for (int off = 32; off > 0; off >>= 1) {
    float m2 = __shfl_xor(m, off);
    float s2 = __shfl_xor(s, off);
    lse_merge(m, s, m2, s2);
  }
  __shared__ float sm[4], ss[4];
  if ((t & 63) == 0) { sm[t >> 6] = m; ss[t >> 6] = s; }
  __syncthreads();
  if (t == 0) {
    float M = sm[0], S = ss[0];
    lse_merge(M, S, sm[1], ss[1]);
    lse_merge(M, S, sm[2], ss[2]);
    lse_merge(M, S, sm[3], ss[3]);
    r[i] = M + __logf(S);
  }
}

// partial col lse over 64-row chunks (256 blocks -> 1/CU); thread = 4 cols
__global__ __launch_bounds__(256) void k_col_partial(const float* __restrict__ w,
                                                     const float* __restrict__ r,
                                                     float* __restrict__ pm,
                                                     float* __restrict__ ps) {
  const int j4 = blockIdx.x * 256 + threadIdx.x;   // 0..1023
  const int i0 = blockIdx.y * 64;
  float m0 = -INFINITY, m1 = -INFINITY, m2 = -INFINITY, m3 = -INFINITY;
  float s0 = 0.f, s1 = 0.f, s2 = 0.f, s3 = 0.f;
  const f32x4* __restrict__ w4 = (const f32x4*)w;
  #pragma unroll 4
  for (int ii = 0; ii < 64; ++ii) {
    const int i = i0 + ii;
    const float rr = r[i];
    f32x4 v = w4[(size_t)i * (DD / 4) + j4];
    lse_acc(m0, s0, v[0] - rr);
    lse_acc(m1, s1, v[1] - rr);
    lse_acc(m2, s2, v[2] - rr);
    lse_acc(m3, s3, v[3] - rr);
  }
  f32x4 mv; mv[0] = m0; mv[1] = m1; mv[2] = m2; mv[3] = m3;
  f32x4 sv; sv[0] = s0; sv[1] = s1; sv[2] = s2; sv[3] = s3;
  ((f32x4*)pm)[(size_t)blockIdx.y * (DD / 4) + j4] = mv;
  ((f32x4*)ps)[(size_t)blockIdx.y * (DD / 4) + j4] = sv;
}

__global__ __launch_bounds__(256) void k_col_final(const float* __restrict__ pm,
                                                   const float* __restrict__ ps,
                                                   float* __restrict__ c) {
  const int j4 = blockIdx.x * 256 + threadIdx.x;  // 0..1023
  const f32x4* __restrict__ pm4 = (const f32x4*)pm;
  const f32x4* __restrict__ ps4 = (const f32x4*)ps;
  float m0 = -INFINITY, m1 = -INFINITY, m2 = -INFINITY, m3 = -INFINITY;
  float s0 = 0.f, s1 = 0.f, s2 = 0.f, s3 = 0.f;
  #pragma unroll 4
  for (int k = 0; k < 64; ++k) {
    f32x4 mv = pm4[(size_t)k * (DD / 4) + j4];
    f32x4 sv = ps4[(size_t)k * (DD / 4) + j4];
    lse_merge(m0, s0, mv[0], sv[0]);
    lse_merge(m1, s1, mv[1], sv[1]);
    lse_merge(m2, s2, mv[2], sv[2]);
    lse_merge(m3, s3, mv[3], sv[3]);
  }
  f32x4 cv;
  cv[0] = m0 + __logf(s0);
  cv[1] = m1 + __logf(s1);
  cv[2] = m2 + __logf(s2);
  cv[3] = m3 + __logf(s3);
  ((f32x4*)c)[j4] = cv;
}

// P = exp(w - r - c) -> f32 out; also bf16 P^T into ws (LDS tiled transpose)
__global__ __launch_bounds__(256) void k_pfinal(const float* __restrict__ w,
                                                const float* __restrict__ r,
                                                const float* __restrict__ c,
                                                float* __restrict__ P,
                                                __hip_bfloat16* __restrict__ Bt) {
  __shared__ __hip_bfloat16 tile[64][68];
  const int t = threadIdx.x;
  const int txg = t & 15;   // col group of 4
  const int ty = t >> 4;    // 0..15
  const int bi = blockIdx.y * 64;
  const int bj = blockIdx.x * 64;
  const f32x4* __restrict__ w4 = (const f32x4*)w;
  const f32x4* __restrict__ c4 = (const f32x4*)c;
  f32x4* __restrict__ P4 = (f32x4*)P;
  #pragma unroll
  for (int p = 0; p < 4; ++p) {
    int rr = p * 16 + ty;
    int gi = bi + rr;
    int gj4 = (bj >> 2) + txg;
    f32x4 wv = w4[(size_t)gi * (DD / 4) + gj4];
    f32x4 cv = c4[gj4];
    const float ri = r[gi];
    f32x4 pv;
    #pragma unroll
    for (int q = 0; q < 4; ++q) {
      pv[q] = __expf(wv[q] - ri - cv[q]);
      tile[rr][txg * 4 + q] = __float2bfloat16(pv[q]);
    }
    P4[(size_t)gi * (DD / 4) + gj4] = pv;
  }
  __syncthreads();
  typedef __attribute__((ext_vector_type(4))) short short4v;
  #pragma unroll
  for (int p = 0; p < 4; ++p) {
    int rr = p * 16 + ty;       // row of Bt-tile = col of P-tile
    int gj = bj + rr;
    short4v o;
    #pragma unroll
    for (int q = 0; q < 4; ++q)
      o[q] = *(const short*)&tile[txg * 4 + q][rr];
    *(short4v*)&Bt[(size_t)gj * DD + bi + txg * 4] = o;
  }
}

// ---------------- GEMM: 256x256 tile, BK=64, 8-phase, persistent 4 M-subtiles --
// Phase-read balance 8/4/8/4 (was 8/4/12/0): P4's RD precedes its overwriting
// STG, which is issued after P4's lgkmcnt(0) (read provably complete).
__global__ __launch_bounds__(512, 2) void k_gemm256(const __hip_bfloat16* __restrict__ A,
                                                    const __hip_bfloat16* __restrict__ Bt,
                                                    float* __restrict__ C) {
  __shared__ alignas(16) char lds[131072];
  const int tid = threadIdx.x;
  const int lane = tid & 63;
  const int wid = tid >> 6;
  const int wm = wid >> 2;   // 0..1
  const int wn = wid & 3;    // 0..3

  // XCD-aware swizzle: 256 wgs = 8 XCDs x 32 (bijective)
  const int bid = blockIdx.x;
  const int swz = (bid & 7) * 32 + (bid >> 3);
  const int ntile = swz & 15;   // 0..15
  const int mgroup = swz >> 4;  // 0..15
  const size_t brow = (size_t)ntile * 256;

  const int srow = tid >> 2;
  const int scolb = ((tid & 3) << 4) ^ (((tid >> 5) & 1) << 5);
  const __hip_bfloat16* gB = Bt + (brow + srow) * (size_t)DD + (scolb >> 1);
  const __hip_bfloat16* gAcur =
      A + ((size_t)mgroup * 4 * 256 + srow) * (size_t)DD + (scolb >> 1);

#define STG(gbase, regionoff, kt, ks) do {                                        \
    const __hip_bfloat16* _g = (gbase) + (kt) * 64 + (ks) * 32;                   \
    char* _l = lds + (regionoff) + (((kt) & 1) * 32768) + (ks) * 16384 + tid * 16;\
    gload_lds16(_g, _l);                                                          \
    gload_lds16(_g + (size_t)128 * DD, _l + 8192);                                \
  } while (0)
#define STG_A(kt, ks) STG(gAcur, 0, kt, ks)
#define STG_B(kt, ks) STG(gB, 65536, kt, ks)

  // read addressing: lane reads row = base + (lane&15), 16B at swizzled col
  const int lr = lane & 15;
  const int rcol = ((lane >> 4) << 4) ^ (((lr >> 3) & 1) << 5);
  const int rbA = (wm * 128 + lr) * 64 + rcol;
  const int rbB = (wn * 64 + lr) * 64 + rcol;

#define LD8(off) (*reinterpret_cast<const short8*>(lds + (off)))
#define RD_B(BUF, KS)                                                   \
  { b[0] = LD8(65536 + (BUF) * 32768 + (KS) * 16384 + rbB + 0);         \
    b[1] = LD8(65536 + (BUF) * 32768 + (KS) * 16384 + rbB + 1024);      \
    b[2] = LD8(65536 + (BUF) * 32768 + (KS) * 16384 + rbB + 2048);      \
    b[3] = LD8(65536 + (BUF) * 32768 + (KS) * 16384 + rbB + 3072); }
#define RD_A4(BUF, KS, MH, DST)                                                   \
  { a[(DST) + 0] = LD8((BUF) * 32768 + (KS) * 16384 + rbA + (MH) * 4096 + 0);     \
    a[(DST) + 1] = LD8((BUF) * 32768 + (KS) * 16384 + rbA + (MH) * 4096 + 1024);  \
    a[(DST) + 2] = LD8((BUF) * 32768 + (KS) * 16384 + rbA + (MH) * 4096 + 2048);  \
    a[(DST) + 3] = LD8((BUF) * 32768 + (KS) * 16384 + rbA + (MH) * 4096 + 3072); }

#define BAR __builtin_amdgcn_s_barrier()
#define LGKM0 asm volatile("s_waitcnt lgkmcnt(0)" ::: "memory")
#define VM6 asm volatile("s_waitcnt vmcnt(6)" ::: "memory")
#define VM0 asm volatile("s_waitcnt vmcnt(0)" ::: "memory")

#define MFMA16(MH)                                                                \
  __builtin_amdgcn_s_setprio(1);                                                  \
  { _Pragma("unroll") for (int i = 0; i < 4; ++i) {                               \
      _Pragma("unroll") for (int n = 0; n < 4; ++n) {                             \
        acc[(MH) * 4 + i][n] = __builtin_amdgcn_mfma_f32_16x16x32_bf16(           \
            a[(MH) * 4 + i], b[n], acc[(MH) * 4 + i][n], 0, 0, 0); } } }          \
  __builtin_amdgcn_s_setprio(0);

  // reads: P1={B ks0, A mh0 ks0}=8, P2={A mh1 ks0}=4, P3={B ks1, A mh0 ks1}=8,
  // P4={A mh1 ks1}=4. stages: P1=next.B1, P2=next2.B0, P3=next2.A0,
  // P4=next2.A1 (after lgkmcnt(0): P4's read of BUF ks1 completed first).
#define KTILE(BUF, TN1, TN2)            \
  RD_B(BUF, 0); RD_A4(BUF, 0, 0, 0);    \
  STG_B(TN1, 1);                        \
  BAR; LGKM0; MFMA16(0); BAR;           \
  RD_A4(BUF, 0, 1, 4);                  \
  STG_B(TN2, 0);                        \
  BAR; LGKM0; MFMA16(1); BAR;           \
  RD_B(BUF, 1); RD_A4(BUF, 1, 0, 0);    \
  STG_A(TN2, 0);                        \
  BAR; LGKM0; MFMA16(0); BAR;           \
  RD_A4(BUF, 1, 1, 4);                  \
  BAR; LGKM0;                           \
  STG_A(TN2, 1); VM6;                   \
  MFMA16(1); BAR;

  // final K-tile pair (kt=62,63): only B(63,ks1) still needs staging; vmcnt(0)
  // in F0-P4 so nothing is in flight at the sub-tile boundary.
#define KTILE_F0                        \
  RD_B(0, 0); RD_A4(0, 0, 0, 0);        \
  STG_B(63, 1);                         \
  BAR; LGKM0; MFMA16(0); BAR;           \
  RD_A4(0, 0, 1, 4);                    \
  BAR; LGKM0; MFMA16(1); BAR;           \
  RD_B(0, 1); RD_A4(0, 1, 0, 0);        \
  BAR; LGKM0; MFMA16(0); BAR;           \
  RD_A4(0, 1, 1, 4);                    \
  BAR; LGKM0; VM0; MFMA16(1); BAR;

#define KTILE_F1                        \
  RD_B(1, 0); RD_A4(1, 0, 0, 0);        \
  BAR; LGKM0; MFMA16(0); BAR;           \
  RD_A4(1, 0, 1, 4);                    \
  BAR; LGKM0; MFMA16(1); BAR;           \
  RD_B(1, 1); RD_A4(1, 1, 0, 0);        \
  BAR; LGKM0; MFMA16(0); BAR;           \
  RD_A4(1, 1, 1, 4);                    \
  BAR; LGKM0; MFMA16(1); BAR;

  f32x4 acc[8][4];
  short8 a[8], b[4];

  // cold prologue: tile 0 (all 4 halves) + tile 1 {B0,A0,A1}
  STG_B(0, 0); STG_A(0, 0); STG_A(0, 1); STG_B(0, 1);
  STG_B(1, 0); STG_A(1, 0); STG_A(1, 1);
  VM6;
  BAR;

  for (int st = 0; st < 4; ++st) {
    #pragma unroll
    for (int i = 0; i < 8; ++i)
      #pragma unroll
      for (int n = 0; n < 4; ++n) {
        acc[i][n][0] = 0.f; acc[i][n][1] = 0.f; acc[i][n][2] = 0.f; acc[i][n][3] = 0.f;
      }

    for (int kt = 0; kt < 62; kt += 2) {
      KTILE(0, kt + 1, kt + 2);
      KTILE(1, kt + 2, kt + 3);
    }
    KTILE_F0;
    KTILE_F1;

    const size_t arow = (size_t)(mgroup * 4 + st) * 256;

    if (st < 3) {
      // boundary prologue for next sub-tile (before stores -> fill hides)
      const __hip_bfloat16* gAn = gAcur + (size_t)256 * DD;
      STG(gB, 65536, 0, 0); STG(gAn, 0, 0, 0); STG(gAn, 0, 0, 1); STG(gB, 65536, 0, 1);
      STG(gB, 65536, 1, 0); STG(gAn, 0, 1, 0); STG(gAn, 0, 1, 1);
      gAcur = gAn;
    }

    // epilogue: C/D layout col = lane&15, row = (lane>>4)*4 + reg
    const int orow = (lane >> 4) * 4;
    const int ocol = lane & 15;
    #pragma unroll
    for (int mh = 0; mh < 2; ++mh) {
      #pragma unroll
      for (int i = 0; i < 4; ++i) {
        #pragma unroll
        for (int n = 0; n < 4; ++n) {
          #pragma unroll
          for (int jj = 0; jj < 4; ++jj) {
            size_t rrow = arow + (size_t)wm * 128 + mh * 64 + i * 16 + orow + jj;
            size_t ccol = brow + (size_t)wn * 64 + n * 16 + ocol;
            C[rrow * DD + ccol] = acc[mh * 4 + i][n][jj];
          }
        }
      }
    }

    if (st < 3) { VM6; BAR; }
  }
#undef STG
#undef STG_A
#undef STG_B
#undef LD8
#undef RD_B
#undef RD_A4
#undef BAR
#undef LGKM0
#undef VM6
#undef VM0
#undef MFMA16
#undef KTILE
#undef KTILE_F0
#undef KTILE_F1
}

extern "C" void kernel_launch(void* const* d_in, const int* in_sizes, int n_in,
                              void* d_out, int out_size, void* d_ws, size_t ws_size,
                              hipStream_t stream) {
  const float* x = (const float*)d_in[0];
  const float* w = (const float*)d_in[1];
  float* outMM = (float*)d_out;                        // [16384][4096]
  float* outP = (float*)d_out + (size_t)NROWS * DD;    // [4096][4096]

  char* ws = (char*)d_ws;
  __hip_bfloat16* A = (__hip_bfloat16*)ws;                                   // 128MB
  __hip_bfloat16* Bt = (__hip_bfloat16*)(ws + (size_t)NROWS * DD * 2);       // 32MB
  float* r = (float*)(ws + (size_t)NROWS * DD * 2 + (size_t)DD * DD * 2);
  float* c = r + DD;
  float* pm = c + DD;
  float* ps = pm + 64 * DD;

  k_fftmag<<<NROWS, 256, 0, stream>>>(x, A);
  for (int it = 0; it < 5; ++it) {
    k_row_lse<<<DD, 256, 0, stream>>>(w, it == 0 ? (const float*)nullptr : c, r);
    k_col_partial<<<dim3(4, 64), 256, 0, stream>>>(w, r, pm, ps);
    k_col_final<<<4, 256, 0, stream>>>(pm, ps, c);
  }
  k_pfinal<<<dim3(64, 64), 256, 0, stream>>>(w, r, c, outP, Bt);
  k_gemm256<<<256, 512, 0, stream>>>(A, Bt, outMM);
}

// Round 8
// 809.450 us; speedup vs baseline: 1.0643x; 1.0622x over previous
//
#include <hip/hip_runtime.h>
#include <hip/hip_bf16.h>
#include <math.h>

#define NROWS 16384
#define DD 4096

typedef __attribute__((ext_vector_type(8))) short short8;
typedef __attribute__((ext_vector_type(4))) float f32x4;

typedef const __attribute__((address_space(1))) void* gas_cvp;
typedef __attribute__((address_space(3))) void* las_vp;

__device__ __forceinline__ void gload_lds16(const void* g, void* l) {
  __builtin_amdgcn_global_load_lds((gas_cvp)g, (las_vp)l, 16, 0, 0);
}

// ---------------- 16-point FFT in registers (two radix-4 stages) ----------------
__device__ __forceinline__ void dft4(float ar, float ai, float br, float bi,
                                     float cr, float ci, float dr, float di,
                                     float& y0r, float& y0i, float& y1r, float& y1i,
                                     float& y2r, float& y2i, float& y3r, float& y3i) {
  float t0r = ar + cr, t0i = ai + ci;
  float t1r = ar - cr, t1i = ai - ci;
  float t2r = br + dr, t2i = bi + di;
  float t3r = br - dr, t3i = bi - di;
  y0r = t0r + t2r; y0i = t0i + t2i;
  y2r = t0r - t2r; y2i = t0i - t2i;
  y1r = t1r + t3i; y1i = t1i - t3r;
  y3r = t1r - t3i; y3i = t1i + t3r;
}

#define C16_1 0.9238795325112867f
#define S16_1 0.3826834323650898f
#define C16_2 0.7071067811865476f

__device__ __forceinline__ void fft16(float* xr, float* xi) {
  const float W16R[10] = {1.f,  C16_1,  C16_2,  S16_1, 0.f, -S16_1, -C16_2, -C16_1, -1.f, -C16_1};
  const float W16I[10] = {0.f, -S16_1, -C16_2, -C16_1, -1.f, -C16_1, -C16_2, -S16_1, 0.f,  S16_1};
  float gr[16], gi[16];
  #pragma unroll
  for (int n2 = 0; n2 < 4; ++n2) {
    dft4(xr[n2], xi[n2], xr[4 + n2], xi[4 + n2], xr[8 + n2], xi[8 + n2], xr[12 + n2], xi[12 + n2],
         gr[0 * 4 + n2], gi[0 * 4 + n2], gr[1 * 4 + n2], gi[1 * 4 + n2],
         gr[2 * 4 + n2], gi[2 * 4 + n2], gr[3 * 4 + n2], gi[3 * 4 + n2]);
  }
  #pragma unroll
  for (int k1 = 1; k1 < 4; ++k1) {
    #pragma unroll
    for (int n2 = 1; n2 < 4; ++n2) {
      const float wr = W16R[k1 * n2], wi = W16I[k1 * n2];
      float a = gr[k1 * 4 + n2], b = gi[k1 * 4 + n2];
      gr[k1 * 4 + n2] = a * wr - b * wi;
      gi[k1 * 4 + n2] = a * wi + b * wr;
    }
  }
  #pragma unroll
  for (int k1 = 0; k1 < 4; ++k1) {
    dft4(gr[k1 * 4 + 0], gi[k1 * 4 + 0], gr[k1 * 4 + 1], gi[k1 * 4 + 1],
         gr[k1 * 4 + 2], gi[k1 * 4 + 2], gr[k1 * 4 + 3], gi[k1 * 4 + 3],
         xr[k1 + 0], xi[k1 + 0], xr[k1 + 4], xi[k1 + 4],
         xr[k1 + 8], xi[k1 + 8], xr[k1 + 12], xi[k1 + 12]);
  }
}

// twiddle apply x[k] *= w1^k via power-doubling (dep depth 4, not 15)
#define TWIDDLE16(xr, xi, w1r, w1i)                                               \
  {                                                                               \
    float pr[16], pi[16];                                                         \
    pr[1] = (w1r); pi[1] = (w1i);                                                 \
    _Pragma("unroll") for (int _z = 0; _z < 1; ++_z) {                            \
      pr[2] = pr[1]*pr[1] - pi[1]*pi[1];  pi[2] = 2.f*pr[1]*pi[1];                \
      pr[4] = pr[2]*pr[2] - pi[2]*pi[2];  pi[4] = 2.f*pr[2]*pi[2];                \
      pr[8] = pr[4]*pr[4] - pi[4]*pi[4];  pi[8] = 2.f*pr[4]*pi[4];                \
      pr[3] = pr[1]*pr[2] - pi[1]*pi[2];  pi[3] = pr[1]*pi[2] + pi[1]*pr[2];      \
      pr[5] = pr[1]*pr[4] - pi[1]*pi[4];  pi[5] = pr[1]*pi[4] + pi[1]*pr[4];      \
      pr[6] = pr[2]*pr[4] - pi[2]*pi[4];  pi[6] = pr[2]*pi[4] + pi[2]*pr[4];      \
      pr[7] = pr[3]*pr[4] - pi[3]*pi[4];  pi[7] = pr[3]*pi[4] + pi[3]*pr[4];      \
      pr[9] = pr[1]*pr[8] - pi[1]*pi[8];  pi[9] = pr[1]*pi[8] + pi[1]*pr[8];      \
      pr[10] = pr[2]*pr[8] - pi[2]*pi[8]; pi[10] = pr[2]*pi[8] + pi[2]*pr[8];     \
      pr[11] = pr[3]*pr[8] - pi[3]*pi[8]; pi[11] = pr[3]*pi[8] + pi[3]*pr[8];     \
      pr[12] = pr[4]*pr[8] - pi[4]*pi[8]; pi[12] = pr[4]*pi[8] + pi[4]*pr[8];     \
      pr[13] = pr[5]*pr[8] - pi[5]*pi[8]; pi[13] = pr[5]*pi[8] + pi[5]*pr[8];     \
      pr[14] = pr[6]*pr[8] - pi[6]*pi[8]; pi[14] = pr[6]*pi[8] + pi[6]*pr[8];     \
      pr[15] = pr[7]*pr[8] - pi[7]*pi[8]; pi[15] = pr[7]*pi[8] + pi[7]*pr[8];     \
    }                                                                             \
    _Pragma("unroll") for (int k = 1; k < 16; ++k) {                              \
      float aa = (xr)[k], bb = (xi)[k];                                           \
      (xr)[k] = aa * pr[k] - bb * pi[k];                                          \
      (xi)[k] = aa * pi[k] + bb * pr[k];                                          \
    }                                                                             \
  }

// ---------------- FFT magnitude + row-max normalize -> bf16 A ----------------
// Final store goes through an LDS exchange (stride-20 pad) so global writes are
// two fully-coalesced 16B bf16 chunks per lane (was: 2B scatter at 32B stride).
__global__ __launch_bounds__(256) void k_fftmag(const float* __restrict__ x,
                                                __hip_bfloat16* __restrict__ A) {
  __shared__ float lsh[8704];          // lre = lsh[0..4351], lim = lsh[4352..]
  float* lre = lsh;
  float* lim = lsh + 4352;
  const int t = threadIdx.x;
  const size_t row = blockIdx.x;
  const float* __restrict__ xg = x + row * DD;

  float xr[16], xi[16];

  #pragma unroll
  for (int n1 = 0; n1 < 16; ++n1) {
    xr[n1] = xg[n1 * 256 + t];
    xi[n1] = 0.0f;
  }
  fft16(xr, xi);
  {
    float w1r, w1i;
    __sincosf(-6.283185307179586f * (float)t / 4096.0f, &w1i, &w1r);
    TWIDDLE16(xr, xi, w1r, w1i);
  }
  #pragma unroll
  for (int k1 = 0; k1 < 16; ++k1) {
    lre[k1 * 272 + t] = xr[k1];
    lim[k1 * 272 + t] = xi[k1];
  }
  __syncthreads();

  const int k1 = t >> 4;
  const int m2 = t & 15;
  #pragma unroll
  for (int m1 = 0; m1 < 16; ++m1) {
    xr[m1] = lre[k1 * 272 + m1 * 16 + m2];
    xi[m1] = lim[k1 * 272 + m1 * 16 + m2];
  }
  fft16(xr, xi);
  {
    float w1r, w1i;
    __sincosf(-6.283185307179586f * (float)m2 / 256.0f, &w1i, &w1r);
    TWIDDLE16(xr, xi, w1r, w1i);
  }
  __syncthreads();
  #pragma unroll
  for (int j1 = 0; j1 < 16; ++j1) {
    lre[j1 * 256 + k1 * 16 + (m2 ^ j1)] = xr[j1];
    lim[j1 * 256 + k1 * 16 + (m2 ^ j1)] = xi[j1];
  }
  __syncthreads();

  const int j1 = t & 15;
  #pragma unroll
  for (int mm = 0; mm < 16; ++mm) {
    xr[mm] = lre[j1 * 256 + k1 * 16 + (mm ^ j1)];
    xi[mm] = lim[j1 * 256 + k1 * 16 + (mm ^ j1)];
  }
  fft16(xr, xi);

  // output col of xr[j2]: c = k1 + 16*j1 + 256*j2  (u = c>>4 = j1+16*j2, c&15 = k1)
  float mag[16];
  float mx = 0.0f;
  #pragma unroll
  for (int j2 = 0; j2 < 16; ++j2) {
    float m = sqrtf(xr[j2] * xr[j2] + xi[j2] * xi[j2]);
    mag[j2] = m;
    mx = fmaxf(mx, m);
  }
  #pragma unroll
  for (int off = 32; off > 0; off >>= 1) mx = fmaxf(mx, __shfl_xor(mx, off));
  __shared__ float wmax[4];
  if ((t & 63) == 0) wmax[t >> 6] = mx;
  __syncthreads();   // also guarantees all pass-3 LDS reads are complete
  mx = fmaxf(fmaxf(wmax[0], wmax[1]), fmaxf(wmax[2], wmax[3]));
  const float inv = 1.0f / (mx + 1e-6f);

  // exchange: lsh[u*20 + k1] = mag, u = j1 + 16*j2  (stride-20 pad, 16B-aligned reads)
  #pragma unroll
  for (int j2 = 0; j2 < 16; ++j2) {
    lsh[(j1 + 16 * j2) * 20 + k1] = mag[j2];
  }
  __syncthreads();

  // thread t writes cols [8t, 8t+8) and [2048+8t, 2048+8t+8): u = t>>1 (+128), k1 = 8*(t&1)+e
  const int q = t >> 1;
  const int h = (t & 1) * 8;
  short8 o0, o1;
  #pragma unroll
  for (int e = 0; e < 8; ++e) {
    float v0 = lsh[q * 20 + h + e] * inv;
    float v1 = lsh[(128 + q) * 20 + h + e] * inv;
    __hip_bfloat16 b0 = __float2bfloat16(v0);
    __hip_bfloat16 b1 = __float2bfloat16(v1);
    o0[e] = *(const short*)&b0;
    o1[e] = *(const short*)&b1;
  }
  *(short8*)&A[row * DD + 8 * t] = o0;
  *(short8*)&A[row * DD + 2048 + 8 * t] = o1;
}

// ---------------- Sinkhorn: log_P = w - r_i - c_j (outer form) ----------------
__device__ __forceinline__ void lse_acc(float& m, float& s, float v) {
  float nm = fmaxf(m, v);
  s = s * __expf(m - nm) + __expf(v - nm);
  m = nm;
}
__device__ __forceinline__ void lse_merge(float& m, float& s, float m2, float s2) {
  float nm = fmaxf(m, m2);
  s = s * __expf(m - nm) + s2 * __expf(m2 - nm);
  m = nm;
}

// r_i = lse_j(w_ij - c_j); one block per row, float4 loads; c may be null (== 0)
__global__ __launch_bounds__(256) void k_row_lse(const float* __restrict__ w,
                                                 const float* __restrict__ c,
                                                 float* __restrict__ r) {
  const int i = blockIdx.x;
  const int t = threadIdx.x;
  const f32x4* __restrict__ wr4 = (const f32x4*)(w + (size_t)i * DD);
  const f32x4* __restrict__ c4 = (const f32x4*)c;
  float m = -INFINITY, s = 0.0f;
  #pragma unroll
  for (int u = 0; u < 4; ++u) {
    int j4 = t + u * 256;
    f32x4 wv = wr4[j4];
    f32x4 cv;
    if (c4) cv = c4[j4];
    else { cv[0] = 0.f; cv[1] = 0.f; cv[2] = 0.f; cv[3] = 0.f; }
    #pragma unroll
    for (int q = 0; q < 4; ++q) lse_acc(m, s, wv[q] - cv[q]);
  }
  #pragma unroll
  for (int off = 32; off > 0; off >>= 1) {
    float m2 = __shfl_xor(m, off);
    float s2 = __shfl_xor(s, off);
    lse_merge(m, s, m2, s2);
  }
  __shared__ float sm[4], ss[4];
  if ((t & 63) == 0) { sm[t >> 6] = m; ss[t >> 6] = s; }
  __syncthreads();
  if (t == 0) {
    float M = sm[0], S = ss[0];
    lse_merge(M, S, sm[1], ss[1]);
    lse_merge(M, S, sm[2], ss[2]);
    lse_merge(M, S, sm[3], ss[3]);
    r[i] = M + __logf(S);
  }
}

// partial col lse over 32-row chunks (512 blocks -> 2/CU, 8 waves/CU)
__global__ __launch_bounds__(256) void k_col_partial(const float* __restrict__ w,
                                                     const float* __restrict__ r,
                                                     float* __restrict__ pm,
                                                     float* __restrict__ ps) {
  const int j4 = blockIdx.x * 256 + threadIdx.x;   // 0..1023
  const int i0 = blockIdx.y * 32;
  float m0 = -INFINITY, m1 = -INFINITY, m2 = -INFINITY, m3 = -INFINITY;
  float s0 = 0.f, s1 = 0.f, s2 = 0.f, s3 = 0.f;
  const f32x4* __restrict__ w4 = (const f32x4*)w;
  #pragma unroll 4
  for (int ii = 0; ii < 32; ++ii) {
    const int i = i0 + ii;
    const float rr = r[i];
    f32x4 v = w4[(size_t)i * (DD / 4) + j4];
    lse_acc(m0, s0, v[0] - rr);
    lse_acc(m1, s1, v[1] - rr);
    lse_acc(m2, s2, v[2] - rr);
    lse_acc(m3, s3, v[3] - rr);
  }
  f32x4 mv; mv[0] = m0; mv[1] = m1; mv[2] = m2; mv[3] = m3;
  f32x4 sv; sv[0] = s0; sv[1] = s1; sv[2] = s2; sv[3] = s3;
  ((f32x4*)pm)[(size_t)blockIdx.y * (DD / 4) + j4] = mv;
  ((f32x4*)ps)[(size_t)blockIdx.y * (DD / 4) + j4] = sv;
}

// final merge over 128 chunks; 16 blocks x 256 thr = 64 waves, coalesced scalar
__global__ __launch_bounds__(256) void k_col_final(const float* __restrict__ pm,
                                                   const float* __restrict__ ps,
                                                   float* __restrict__ c) {
  const int j = blockIdx.x * 256 + threadIdx.x;   // 0..4095
  float m = -INFINITY, s = 0.0f;
  #pragma unroll 4
  for (int k = 0; k < 128; ++k) {
    lse_merge(m, s, pm[(size_t)k * DD + j], ps[(size_t)k * DD + j]);
  }
  c[j] = m + __logf(s);
}

// P = exp(w - r - c) -> f32 out; also bf16 P^T into ws (LDS tiled transpose)
__global__ __launch_bounds__(256) void k_pfinal(const float* __restrict__ w,
                                                const float* __restrict__ r,
                                                const float* __restrict__ c,
                                                float* __restrict__ P,
                                                __hip_bfloat16* __restrict__ Bt) {
  __shared__ __hip_bfloat16 tile[64][68];
  const int t = threadIdx.x;
  const int txg = t & 15;   // col group of 4
  const int ty = t >> 4;    // 0..15
  const int bi = blockIdx.y * 64;
  const int bj = blockIdx.x * 64;
  const f32x4* __restrict__ w4 = (const f32x4*)w;
  const f32x4* __restrict__ c4 = (const f32x4*)c;
  f32x4* __restrict__ P4 = (f32x4*)P;
  #pragma unroll
  for (int p = 0; p < 4; ++p) {
    int rr = p * 16 + ty;
    int gi = bi + rr;
    int gj4 = (bj >> 2) + txg;
    f32x4 wv = w4[(size_t)gi * (DD / 4) + gj4];
    f32x4 cv = c4[gj4];
    const float ri = r[gi];
    f32x4 pv;
    #pragma unroll
    for (int q = 0; q < 4; ++q) {
      pv[q] = __expf(wv[q] - ri - cv[q]);
      tile[rr][txg * 4 + q] = __float2bfloat16(pv[q]);
    }
    P4[(size_t)gi * (DD / 4) + gj4] = pv;
  }
  __syncthreads();
  typedef __attribute__((ext_vector_type(4))) short short4v;
  #pragma unroll
  for (int p = 0; p < 4; ++p) {
    int rr = p * 16 + ty;       // row of Bt-tile = col of P-tile
    int gj = bj + rr;
    short4v o;
    #pragma unroll
    for (int q = 0; q < 4; ++q)
      o[q] = *(const short*)&tile[txg * 4 + q][rr];
    *(short4v*)&Bt[(size_t)gj * DD + bi + txg * 4] = o;
  }
}

// ---------------- GEMM: 256x256 tile, BK=64, 8-phase, persistent 4 M-subtiles --
// (unchanged from R7: 8/4/8/4 phase balance, 0 bank conflicts, ~503us)
__global__ __launch_bounds__(512, 2) void k_gemm256(const __hip_bfloat16* __restrict__ A,
                                                    const __hip_bfloat16* __restrict__ Bt,
                                                    float* __restrict__ C) {
  __shared__ alignas(16) char lds[131072];
  const int tid = threadIdx.x;
  const int lane = tid & 63;
  const int wid = tid >> 6;
  const int wm = wid >> 2;   // 0..1
  const int wn = wid & 3;    // 0..3

  // XCD-aware swizzle: 256 wgs = 8 XCDs x 32 (bijective)
  const int bid = blockIdx.x;
  const int swz = (bid & 7) * 32 + (bid >> 3);
  const int ntile = swz & 15;   // 0..15
  const int mgroup = swz >> 4;  // 0..15
  const size_t brow = (size_t)ntile * 256;

  const int srow = tid >> 2;
  const int scolb = ((tid & 3) << 4) ^ (((tid >> 5) & 1) << 5);
  const __hip_bfloat16* gB = Bt + (brow + srow) * (size_t)DD + (scolb >> 1);
  const __hip_bfloat16* gAcur =
      A + ((size_t)mgroup * 4 * 256 + srow) * (size_t)DD + (scolb >> 1);

#define STG(gbase, regionoff, kt, ks) do {                                        \
    const __hip_bfloat16* _g = (gbase) + (kt) * 64 + (ks) * 32;                   \
    char* _l = lds + (regionoff) + (((kt) & 1) * 32768) + (ks) * 16384 + tid * 16;\
    gload_lds16(_g, _l);                                                          \
    gload_lds16(_g + (size_t)128 * DD, _l + 8192);                                \
  } while (0)
#define STG_A(kt, ks) STG(gAcur, 0, kt, ks)
#define STG_B(kt, ks) STG(gB, 65536, kt, ks)

  // read addressing: lane reads row = base + (lane&15), 16B at swizzled col
  const int lr = lane & 15;
  const int rcol = ((lane >> 4) << 4) ^ (((lr >> 3) & 1) << 5);
  const int rbA = (wm * 128 + lr) * 64 + rcol;
  const int rbB = (wn * 64 + lr) * 64 + rcol;

#define LD8(off) (*reinterpret_cast<const short8*>(lds + (off)))
#define RD_B(BUF, KS)                                                   \
  { b[0] = LD8(65536 + (BUF) * 32768 + (KS) * 16384 + rbB + 0);         \
    b[1] = LD8(65536 + (BUF) * 32768 + (KS) * 16384 + rbB + 1024);      \
    b[2] = LD8(65536 + (BUF) * 32768 + (KS) * 16384 + rbB + 2048);      \
    b[3] = LD8(65536 + (BUF) * 32768 + (KS) * 16384 + rbB + 3072); }
#define RD_A4(BUF, KS, MH, DST)                                                   \
  { a[(DST) + 0] = LD8((BUF) * 32768 + (KS) * 16384 + rbA + (MH) * 4096 + 0);     \
    a[(DST) + 1] = LD8((BUF) * 32768 + (KS) * 16384 + rbA + (MH) * 4096 + 1024);  \
    a[(DST) + 2] = LD8((BUF) * 32768 + (KS) * 16384 + rbA + (MH) * 4096 + 2048);  \
    a[(DST) + 3] = LD8((BUF) * 32768 + (KS) * 16384 + rbA + (MH) * 4096 + 3072); }

#define BAR __builtin_amdgcn_s_barrier()
#define LGKM0 asm volatile("s_waitcnt lgkmcnt(0)" ::: "memory")
#define VM6 asm volatile("s_waitcnt vmcnt(6)" ::: "memory")
#define VM0 asm volatile("s_waitcnt vmcnt(0)" ::: "memory")

#define MFMA16(MH)                                                                \
  __builtin_amdgcn_s_setprio(1);                                                  \
  { _Pragma("unroll") for (int i = 0; i < 4; ++i) {                               \
      _Pragma("unroll") for (int n = 0; n < 4; ++n) {                             \
        acc[(MH) * 4 + i][n] = __builtin_amdgcn_mfma_f32_16x16x32_bf16(           \
            a[(MH) * 4 + i], b[n], acc[(MH) * 4 + i][n], 0, 0, 0); } } }          \
  __builtin_amdgcn_s_setprio(0);

#define KTILE(BUF, TN1, TN2)            \
  RD_B(BUF, 0); RD_A4(BUF, 0, 0, 0);    \
  STG_B(TN1, 1);                        \
  BAR; LGKM0; MFMA16(0); BAR;           \
  RD_A4(BUF, 0, 1, 4);                  \
  STG_B(TN2, 0);                        \
  BAR; LGKM0; MFMA16(1); BAR;           \
  RD_B(BUF, 1); RD_A4(BUF, 1, 0, 0);    \
  STG_A(TN2, 0);                        \
  BAR; LGKM0; MFMA16(0); BAR;           \
  RD_A4(BUF, 1, 1, 4);                  \
  BAR; LGKM0;                           \
  STG_A(TN2, 1); VM6;                   \
  MFMA16(1); BAR;

#define KTILE_F0                        \
  RD_B(0, 0); RD_A4(0, 0, 0, 0);        \
  STG_B(63, 1);                         \
  BAR; LGKM0; MFMA16(0); BAR;           \
  RD_A4(0, 0, 1, 4);                    \
  BAR; LGKM0; MFMA16(1); BAR;           \
  RD_B(0, 1); RD_A4(0, 1, 0, 0);        \
  BAR; LGKM0; MFMA16(0); BAR;           \
  RD_A4(0, 1, 1, 4);                    \
  BAR; LGKM0; VM0; MFMA16(1); BAR;

#define KTILE_F1                        \
  RD_B(1, 0); RD_A4(1, 0, 0, 0);        \
  BAR; LGKM0; MFMA16(0); BAR;           \
  RD_A4(1, 0, 1, 4);                    \
  BAR; LGKM0; MFMA16(1); BAR;           \
  RD_B(1, 1); RD_A4(1, 1, 0, 0);        \
  BAR; LGKM0; MFMA16(0); BAR;           \
  RD_A4(1, 1, 1, 4);                    \
  BAR; LGKM0; MFMA16(1); BAR;

  f32x4 acc[8][4];
  short8 a[8], b[4];

  // cold prologue: tile 0 (all 4 halves) + tile 1 {B0,A0,A1}
  STG_B(0, 0); STG_A(0, 0); STG_A(0, 1); STG_B(0, 1);
  STG_B(1, 0); STG_A(1, 0); STG_A(1, 1);
  VM6;
  BAR;

  for (int st = 0; st < 4; ++st) {
    #pragma unroll
    for (int i = 0; i < 8; ++i)
      #pragma unroll
      for (int n = 0; n < 4; ++n) {
        acc[i][n][0] = 0.f; acc[i][n][1] = 0.f; acc[i][n][2] = 0.f; acc[i][n][3] = 0.f;
      }

    for (int kt = 0; kt < 62; kt += 2) {
      KTILE(0, kt + 1, kt + 2);
      KTILE(1, kt + 2, kt + 3);
    }
    KTILE_F0;
    KTILE_F1;

    const size_t arow = (size_t)(mgroup * 4 + st) * 256;

    if (st < 3) {
      // boundary prologue for next sub-tile (before stores -> fill hides)
      const __hip_bfloat16* gAn = gAcur + (size_t)256 * DD;
      STG(gB, 65536, 0, 0); STG(gAn, 0, 0, 0); STG(gAn, 0, 0, 1); STG(gB, 65536, 0, 1);
      STG(gB, 65536, 1, 0); STG(gAn, 0, 1, 0); STG(gAn, 0, 1, 1);
      gAcur = gAn;
    }

    // epilogue: C/D layout col = lane&15, row = (lane>>4)*4 + reg
    const int orow = (lane >> 4) * 4;
    const int ocol = lane & 15;
    #pragma unroll
    for (int mh = 0; mh < 2; ++mh) {
      #pragma unroll
      for (int i = 0; i < 4; ++i) {
        #pragma unroll
        for (int n = 0; n < 4; ++n) {
          #pragma unroll
          for (int jj = 0; jj < 4; ++jj) {
            size_t rrow = arow + (size_t)wm * 128 + mh * 64 + i * 16 + orow + jj;
            size_t ccol = brow + (size_t)wn * 64 + n * 16 + ocol;
            C[rrow * DD + ccol] = acc[mh * 4 + i][n][jj];
          }
        }
      }
    }

    if (st < 3) { VM6; BAR; }
  }
#undef STG
#undef STG_A
#undef STG_B
#undef LD8
#undef RD_B
#undef RD_A4
#undef BAR
#undef LGKM0
#undef VM6
#undef VM0
#undef MFMA16
#undef KTILE
#undef KTILE_F0
#undef KTILE_F1
}

extern "C" void kernel_launch(void* const* d_in, const int* in_sizes, int n_in,
                              void* d_out, int out_size, void* d_ws, size_t ws_size,
                              hipStream_t stream) {
  const float* x = (const float*)d_in[0];
  const float* w = (const float*)d_in[1];
  float* outMM = (float*)d_out;                        // [16384][4096]
  float* outP = (float*)d_out + (size_t)NROWS * DD;    // [4096][4096]

  char* ws = (char*)d_ws;
  __hip_bfloat16* A = (__hip_bfloat16*)ws;                                   // 128MB
  __hip_bfloat16* Bt = (__hip_bfloat16*)(ws + (size_t)NROWS * DD * 2);       // 32MB
  float* r = (float*)(ws + (size_t)NROWS * DD * 2 + (size_t)DD * DD * 2);
  float* c = r + DD;
  float* pm = c + DD;
  float* ps = pm + 128 * DD;

  k_fftmag<<<NROWS, 256, 0, stream>>>(x, A);
  for (int it = 0; it < 5; ++it) {
    k_row_lse<<<DD, 256, 0, stream>>>(w, it == 0 ? (const float*)nullptr : c, r);
    k_col_partial<<<dim3(4, 128), 256, 0, stream>>>(w, r, pm, ps);
    k_col_final<<<16, 256, 0, stream>>>(pm, ps, c);
  }
  k_pfinal<<<dim3(64, 64), 256, 0, stream>>>(w, r, c, outP, Bt);
  k_gemm256<<<256, 512, 0, stream>>>(A, Bt, outMM);
}